// Round 2
// baseline (31.225 us; speedup 1.0000x reference)
//
#include <hip/hip_runtime.h>
#include <cfloat>
#include <climits>

#define INV_T   (1.0f / 0.07f)
#define SPLIT   8
#define THREADS 256
#define WPB     (THREADS / 64)   // waves per block

struct Partial {
    float m, s, pos_sum, minval;
    int   npos, minidx;
    int   pad0, pad1;            // 32 B
};

__device__ __forceinline__ void sm_combine(float& m, float& s, float m2, float s2) {
    float mm = fmaxf(m, m2);
    s = s * __expf(m - mm) + s2 * __expf(m2 - mm);
    m = mm;
}

__device__ __forceinline__ void accum_elem(
    float lv, unsigned p, unsigned cam, unsigned tgt, int gidx,
    float& m, float& s, float& pos_sum, int& npos, float& minval, int& minidx)
{
    if ((p & 15u) == cam) {
        float a = lv * INV_T;
        if (a > m) { s *= __expf(m - a); m = a; }
        s += __expf(a - m);
        if (p == tgt) {
            npos    += 1;
            pos_sum += a;
            if (lv < minval || (lv == minval && gidx < minidx)) {
                minval = lv; minidx = gidx;
            }
        }
    }
}

__global__ __launch_bounds__(256) void wscl_pack(
    const int* __restrict__ cid, const int* __restrict__ tidv,
    ushort* __restrict__ packed, int N)
{
    const int i  = blockIdx.x * 256 + threadIdx.x;
    const int N4 = N >> 2;
    if (i < N4) {
        int4 c = ((const int4*)cid)[i];
        int4 r = ((const int4*)tidv)[i];
        ushort4 p;
        p.x = (ushort)((c.x & 15) | (r.x << 4));
        p.y = (ushort)((c.y & 15) | (r.y << 4));
        p.z = (ushort)((c.z & 15) | (r.z << 4));
        p.w = (ushort)((c.w & 15) | (r.w << 4));
        ((ushort4*)packed)[i] = p;
    }
    const int j = (N4 << 2) + i;
    if (i < (N & 3) && j < N)
        packed[j] = (ushort)((cid[j] & 15) | (tidv[j] << 4));
}

__global__ __launch_bounds__(THREADS) void wscl_partial(
    const float*  __restrict__ logits,
    const ushort* __restrict__ packed,
    const int*    __restrict__ camids,
    const int*    __restrict__ trackids,
    Partial*      __restrict__ partials,
    int N)
{
    const int b   = blockIdx.x / SPLIT;
    const int sp  = blockIdx.x % SPLIT;
    const int t   = threadIdx.x;
    const unsigned cam = (unsigned)(camids[b] & 15);
    const unsigned tgt = cam | ((unsigned)trackids[b] << 4);
    const float* lg = logits + (size_t)b * N;

    float m = -FLT_MAX, s = 0.0f, pos_sum = 0.0f, minval = FLT_MAX;
    int npos = 0, minidx = INT_MAX;

    const int NG    = N >> 3;
    const int chunk = (NG + SPLIT - 1) / SPLIT;
    const int i0    = sp * chunk;
    const int i1    = (i0 + chunk < NG) ? (i0 + chunk) : NG;
    const float4* lg4 = (const float4*)lg;
    const uint4*  pk4 = (const uint4*)packed;

    for (int i = i0 + t; i < i1; i += THREADS) {
        float4 v0 = lg4[2 * i + 0];
        float4 v1 = lg4[2 * i + 1];
        uint4  pk = pk4[i];
        int g = i * 8;
        accum_elem(v0.x, pk.x & 0xFFFFu, cam, tgt, g + 0, m, s, pos_sum, npos, minval, minidx);
        accum_elem(v0.y, pk.x >> 16,     cam, tgt, g + 1, m, s, pos_sum, npos, minval, minidx);
        accum_elem(v0.z, pk.y & 0xFFFFu, cam, tgt, g + 2, m, s, pos_sum, npos, minval, minidx);
        accum_elem(v0.w, pk.y >> 16,     cam, tgt, g + 3, m, s, pos_sum, npos, minval, minidx);
        accum_elem(v1.x, pk.z & 0xFFFFu, cam, tgt, g + 4, m, s, pos_sum, npos, minval, minidx);
        accum_elem(v1.y, pk.z >> 16,     cam, tgt, g + 5, m, s, pos_sum, npos, minval, minidx);
        accum_elem(v1.z, pk.w & 0xFFFFu, cam, tgt, g + 6, m, s, pos_sum, npos, minval, minidx);
        accum_elem(v1.w, pk.w >> 16,     cam, tgt, g + 7, m, s, pos_sum, npos, minval, minidx);
    }
    if (sp == SPLIT - 1) {
        for (int j = (NG << 3) + t; j < N; j += THREADS)
            accum_elem(lg[j], packed[j], cam, tgt, j, m, s, pos_sum, npos, minval, minidx);
    }

    // phase 1: wave max-reduce (m) + argmin-reduce; keep per-thread m_old
    const float m_old = m;
    for (int off = 32; off > 0; off >>= 1) {
        float m2 = __shfl_xor(m, off);
        float v2 = __shfl_xor(minval, off);
        int   i2 = __shfl_xor(minidx, off);
        m = fmaxf(m, m2);
        if (v2 < minval || (v2 == minval && i2 < minidx)) { minval = v2; minidx = i2; }
    }
    // single rescale per thread: exp(-inf)=0 covers the no-match (m_old=-FLT_MAX) case;
    // if m is still -FLT_MAX (no lane matched), m_old - m == 0 -> s stays 0.
    s *= __expf(m_old - m);

    // phase 2: wave sum-reduce
    for (int off = 32; off > 0; off >>= 1) {
        s       += __shfl_xor(s, off);
        pos_sum += __shfl_xor(pos_sum, off);
        npos    += __shfl_xor(npos, off);
    }

    if ((t & 63) == 0) {
        Partial p;
        p.m = m; p.s = s; p.pos_sum = pos_sum; p.minval = minval;
        p.npos = npos; p.minidx = minidx; p.pad0 = 0; p.pad1 = 0;
        partials[blockIdx.x * WPB + (t >> 6)] = p;
    }
}

__global__ __launch_bounds__(128) void wscl_finalize(
    const Partial* __restrict__ partials,
    const float*   __restrict__ mem,
    float*         __restrict__ out,
    int D, int B, int nper)
{
    const int b = blockIdx.x;
    const int t = threadIdx.x;
    __shared__ float red[128];
    __shared__ int   s_idx;

    if (b == 0) {
        float v = 0.0f;
        for (int bb = t; bb < B; bb += 128) {
            float m = -FLT_MAX, s = 0.0f, pos = 0.0f;
            int np = 0;
            for (int k = 0; k < nper; ++k) {
                Partial p = partials[bb * nper + k];
                sm_combine(m, s, p.m, p.s);
                pos += p.pos_sum; np += p.npos;
            }
            float fn = (float)np;
            v += -((pos - fn * m) - fn * __logf(s)) / fn;
        }
        red[t] = v;
        __syncthreads();
        for (int off = 64; off > 0; off >>= 1) {
            if (t < off) red[t] += red[t + off];
            __syncthreads();
        }
        if (t == 0) out[0] = red[0] / (float)B;
    }

    if (t == 0) {
        float mv = FLT_MAX; int mi = INT_MAX;
        for (int k = 0; k < nper; ++k) {
            Partial p = partials[b * nper + k];
            if (p.minval < mv || (p.minval == mv && p.minidx < mi)) { mv = p.minval; mi = p.minidx; }
        }
        if (mi == INT_MAX) mi = 0;
        s_idx = mi;
    }
    __syncthreads();
    const size_t mi = (size_t)s_idx;
    for (int d = t; d < D; d += 128)
        out[1 + (size_t)b * D + d] = mem[mi * (size_t)D + d];
}

extern "C" void kernel_launch(void* const* d_in, const int* in_sizes, int n_in,
                              void* d_out, int out_size, void* d_ws, size_t ws_size,
                              hipStream_t stream)
{
    const float* mem      = (const float*)d_in[0];
    const float* logits   = (const float*)d_in[1];
    const int*   cid      = (const int*)d_in[2];
    const int*   tidv     = (const int*)d_in[3];
    const int*   camids   = (const int*)d_in[4];
    const int*   trackids = (const int*)d_in[5];

    const int N = in_sizes[2];
    const int B = in_sizes[4];
    const int D = in_sizes[0] / N;

    float* out = (float*)d_out;

    Partial* partials   = (Partial*)d_ws;
    size_t   part_bytes = ((size_t)B * SPLIT * WPB * sizeof(Partial) + 255) & ~(size_t)255;
    ushort*  packed     = (ushort*)((char*)d_ws + part_bytes);

    const int N4 = N >> 2;
    int packGrid = (N4 + 255) / 256; if (packGrid < 1) packGrid = 1;
    wscl_pack<<<packGrid, 256, 0, stream>>>(cid, tidv, packed, N);
    wscl_partial<<<B * SPLIT, THREADS, 0, stream>>>(logits, packed, camids, trackids, partials, N);
    wscl_finalize<<<B, 128, 0, stream>>>(partials, mem, out, D, B, SPLIT * WPB);
}

// Round 3
// 22.901 us; speedup vs baseline: 1.3634x; 1.3634x over previous
//
#include <hip/hip_runtime.h>
#include <cfloat>
#include <climits>

#define INV_T   (1.0f / 0.07f)
#define SPLIT   16
#define THREADS 256

struct Partial {
    float m, s, pos_sum, minval;
    int   npos, minidx;
    int   pad0, pad1;            // 32 B
};

__device__ __forceinline__ void sm_combine(float& m, float& s, float m2, float s2) {
    float mm = fmaxf(m, m2);
    s = s * __expf(m - mm) + s2 * __expf(m2 - mm);
    m = mm;
}

__device__ __forceinline__ void accum(
    float lv, int cc, int tt, int cam, int trk, int gidx,
    float& m, float& s, float& ps, int& np, float& mv, int& mi)
{
    if (cc == cam) {
        float a = lv * INV_T;
        if (a > m) { s *= __expf(m - a); m = a; }
        s += __expf(a - m);
        if (tt == trk) {
            np += 1;
            ps += a;
            if (lv < mv || (lv == mv && gidx < mi)) { mv = lv; mi = gidx; }
        }
    }
}

__global__ __launch_bounds__(THREADS, 8) void wscl_partial(
    const float* __restrict__ logits,
    const int*   __restrict__ cid,
    const int*   __restrict__ tidv,
    const int*   __restrict__ camids,
    const int*   __restrict__ trackids,
    Partial*     __restrict__ partials,
    int N)
{
    const int b   = blockIdx.x / SPLIT;
    const int sp  = blockIdx.x % SPLIT;
    const int t   = threadIdx.x;
    const int cam = camids[b];
    const int trk = trackids[b];
    const float* lg = logits + (size_t)b * N;

    float m = -FLT_MAX, s = 0.0f, ps = 0.0f, mv = FLT_MAX;
    int np = 0, mi = INT_MAX;

    const int N4    = N >> 2;
    const int chunk = (N4 + SPLIT - 1) / SPLIT;
    const int i0    = sp * chunk;
    const int i1    = (i0 + chunk < N4) ? (i0 + chunk) : N4;
    const float4* lg4 = (const float4*)lg;
    const int4*   c4  = (const int4*)cid;
    const int4*   t4  = (const int4*)tidv;

    for (int i = i0 + t; i < i1; i += THREADS) {
        float4 v = lg4[i];
        int4   c = c4[i];
        int4   r = t4[i];
        int g = i * 4;
        accum(v.x, c.x, r.x, cam, trk, g + 0, m, s, ps, np, mv, mi);
        accum(v.y, c.y, r.y, cam, trk, g + 1, m, s, ps, np, mv, mi);
        accum(v.z, c.z, r.z, cam, trk, g + 2, m, s, ps, np, mv, mi);
        accum(v.w, c.w, r.w, cam, trk, g + 3, m, s, ps, np, mv, mi);
    }
    if (sp == SPLIT - 1) {                    // scalar tail (N % 4)
        for (int j = (N4 << 2) + t; j < N; j += THREADS)
            accum(lg[j], cid[j], tidv[j], cam, trk, j, m, s, ps, np, mv, mi);
    }

    // wave reduction: max + argmin first (keep per-thread m_old for single rescale)
    const float m_old = m;
    for (int off = 32; off > 0; off >>= 1) {
        float m2 = __shfl_xor(m, off);
        float v2 = __shfl_xor(mv, off);
        int   i2 = __shfl_xor(mi, off);
        m = fmaxf(m, m2);
        if (v2 < mv || (v2 == mv && i2 < mi)) { mv = v2; mi = i2; }
    }
    s *= __expf(m_old - m);                   // exp(-huge)=0 handles no-match lanes
    for (int off = 32; off > 0; off >>= 1) {
        s  += __shfl_xor(s, off);
        ps += __shfl_xor(ps, off);
        np += __shfl_xor(np, off);
    }

    // cross-wave combine (4 waves) -> one Partial per block
    __shared__ float lm[4], ls[4], lp[4], lv[4];
    __shared__ int   ln[4], li[4];
    const int wid = t >> 6;
    if ((t & 63) == 0) { lm[wid]=m; ls[wid]=s; lp[wid]=ps; lv[wid]=mv; ln[wid]=np; li[wid]=mi; }
    __syncthreads();
    if (t == 0) {
        float M = lm[0], S = ls[0], P = lp[0], V = lv[0];
        int   NP = ln[0], MI = li[0];
        for (int w = 1; w < 4; ++w) {
            sm_combine(M, S, lm[w], ls[w]);
            P += lp[w]; NP += ln[w];
            if (lv[w] < V || (lv[w] == V && li[w] < MI)) { V = lv[w]; MI = li[w]; }
        }
        Partial p; p.m=M; p.s=S; p.pos_sum=P; p.minval=V; p.npos=NP; p.minidx=MI; p.pad0=0; p.pad1=0;
        partials[blockIdx.x] = p;
    }
}

__global__ __launch_bounds__(THREADS) void wscl_finalize(
    const Partial* __restrict__ partials,
    const float*   __restrict__ mem,
    float*         __restrict__ out,
    int D, int B)
{
    const int b = blockIdx.x;
    const int t = threadIdx.x;
    __shared__ float red[128];
    __shared__ int   s_idx;

    // block 0: loss over all anchors (partials are tiny, L2-resident)
    if (b == 0 && t < 128) {
        float v = 0.0f;
        for (int bb = t; bb < B; bb += 128) {
            float m = -FLT_MAX, s = 0.0f, pos = 0.0f;
            int np = 0;
            for (int k = 0; k < SPLIT; ++k) {
                Partial p = partials[bb * SPLIT + k];
                sm_combine(m, s, p.m, p.s);
                pos += p.pos_sum; np += p.npos;
            }
            float fn = (float)np;
            v += -((pos - fn * m) - fn * __logf(s)) / fn;
        }
        red[t] = v;
    }
    // all blocks: argmin combine for own anchor (lanes 0..15 of wave 0)
    float mv = FLT_MAX; int mi = INT_MAX;
    if (t < SPLIT) {
        Partial p = partials[b * SPLIT + t];
        mv = p.minval; mi = p.minidx;
    }
    if (t < 64) {
        for (int off = 8; off > 0; off >>= 1) {
            float v2 = __shfl_xor(mv, off);
            int   i2 = __shfl_xor(mi, off);
            if (v2 < mv || (v2 == mv && i2 < mi)) { mv = v2; mi = i2; }
        }
        if (t == 0) s_idx = (mi == INT_MAX) ? 0 : mi;
    }
    __syncthreads();

    if (b == 0 && t < 128) {
        for (int off = 64; off > 0; off >>= 1) {
            if (t < off) red[t] += red[t + off];
            __syncthreads();
        }
        if (t == 0) out[0] = red[0] / (float)B;
    } else if (b == 0) {
        // keep the non-participating threads at the same __syncthreads count
        for (int off = 64; off > 0; off >>= 1) __syncthreads();
    }

    const size_t row = (size_t)s_idx * (size_t)D;
    for (int d = t; d < D; d += THREADS)
        out[1 + (size_t)b * D + d] = mem[row + d];
}

extern "C" void kernel_launch(void* const* d_in, const int* in_sizes, int n_in,
                              void* d_out, int out_size, void* d_ws, size_t ws_size,
                              hipStream_t stream)
{
    const float* mem      = (const float*)d_in[0];
    const float* logits   = (const float*)d_in[1];
    const int*   cid      = (const int*)d_in[2];
    const int*   tidv     = (const int*)d_in[3];
    const int*   camids   = (const int*)d_in[4];
    const int*   trackids = (const int*)d_in[5];

    const int N = in_sizes[2];
    const int B = in_sizes[4];
    const int D = in_sizes[0] / N;

    float* out = (float*)d_out;
    Partial* partials = (Partial*)d_ws;

    wscl_partial<<<B * SPLIT, THREADS, 0, stream>>>(logits, cid, tidv, camids, trackids, partials, N);
    wscl_finalize<<<B, THREADS, 0, stream>>>(partials, mem, out, D, B);
}